// Round 5
// baseline (8266.479 us; speedup 1.0000x reference)
//
#include <hip/hip_runtime.h>
#include <stdint.h>

typedef unsigned short u16;
typedef __attribute__((ext_vector_type(8))) short short8;
typedef __attribute__((ext_vector_type(4))) float f32x4;

#define T_SEQ 512
#define NB 32
#define EMBD 1024
#define HID 512
#define G4 2048
#define NROWS (T_SEQ * NB)  // 16384
#define XPW 4096
#define WPD 32  // workgroups per direction

static __device__ __forceinline__ u16 f2bf(float x) {
  unsigned u = __float_as_uint(x);
  u += 0x7fffu + ((u >> 16) & 1u);
  return (u16)(u >> 16);
}
static __device__ __forceinline__ float bf2f(u16 b) {
  return __uint_as_float(((unsigned)b) << 16);
}
static __device__ __forceinline__ f32x4 mfma16(short8 a, short8 b, f32x4 c) {
  return __builtin_amdgcn_mfma_f32_16x16x32_bf16(a, b, c, 0, 0, 0);
}

// ---------------- weight prep: bf16 convert, Whh split hi/lo, bias merge ----
__global__ void k_prep(const float* __restrict__ Wih, const float* __restrict__ Whh,
                       const float* __restrict__ bih, const float* __restrict__ bhh,
                       u16* __restrict__ wih_b, u16* __restrict__ whh_hi,
                       u16* __restrict__ whh_lo, float* __restrict__ bcat) {
  size_t stride = (size_t)gridDim.x * blockDim.x;
  size_t i0 = (size_t)blockIdx.x * blockDim.x + threadIdx.x;
  const size_t n_ih = (size_t)2 * 2 * G4 * EMBD;  // [l][d][4H][E]
  for (size_t i = i0; i < n_ih; i += stride) wih_b[i] = f2bf(Wih[i]);
  const size_t n_hh = (size_t)2 * 2 * G4 * HID;   // [l][d][4H][H]
  for (size_t i = i0; i < n_hh; i += stride) {
    float w = Whh[i];
    u16 hi = f2bf(w);
    whh_hi[i] = hi;
    whh_lo[i] = f2bf(w - bf2f(hi));
  }
  for (size_t i = i0; i < 2 * 4096; i += stride) {
    size_t l = i >> 12, col = i & 4095;  // col = d*2048+g*512+u
    bcat[i] = bih[l * 4096 + col] + bhh[l * 4096 + col];
  }
}

// ---------------- embedding gather -> bf16 X [T*B, 1024] --------------------
__global__ void k_gather(const int* __restrict__ inp, const float* __restrict__ emb,
                         u16* __restrict__ X) {
  int row = blockIdx.x;  // t*32 + b
  int t = row >> 5, b = row & 31;
  int tok = inp[b * T_SEQ + t];
  const float* src = emb + (size_t)tok * EMBD + threadIdx.x * 4;
  float4 v = *reinterpret_cast<const float4*>(src);
  ushort4 o;
  o.x = f2bf(v.x); o.y = f2bf(v.y); o.z = f2bf(v.z); o.w = f2bf(v.w);
  *reinterpret_cast<ushort4*>(X + (size_t)row * EMBD + threadIdx.x * 4) = o;
}

// ---------------- xp GEMM: C[M,4096] = A[M,1024] @ B[4096,1024]^T + bias ----
#define GBM 128
#define GBN 128
#define GBK 64
__global__ __launch_bounds__(256) void k_gemm(const u16* __restrict__ A,
                                              const u16* __restrict__ B,
                                              const float* __restrict__ bias,
                                              u16* __restrict__ C) {
  __shared__ u16 As[GBM][GBK];
  __shared__ u16 Bs[GBN][GBK];
  const int Kdim = 1024, Ndim = 4096;
  int bm = blockIdx.x, bn = blockIdx.y;
  int tid = threadIdx.x;
  int lane = tid & 63, wave = tid >> 6;
  int wm = wave >> 1, wn = wave & 1;
  int l15 = lane & 15, klo = (lane >> 4) * 8;
  f32x4 acc[4][4] = {};
  for (int k0 = 0; k0 < Kdim; k0 += GBK) {
#pragma unroll
    for (int s = 0; s < 4; s++) {
      int seg = tid + s * 256;
      int r = seg >> 3, cs = (seg & 7) * 8;
      *reinterpret_cast<short8*>(&As[r][cs]) =
          *reinterpret_cast<const short8*>(A + (size_t)(bm * GBM + r) * Kdim + k0 + cs);
      *reinterpret_cast<short8*>(&Bs[r][cs]) =
          *reinterpret_cast<const short8*>(B + (size_t)(bn * GBN + r) * Kdim + k0 + cs);
    }
    __syncthreads();
#pragma unroll
    for (int kk = 0; kk < GBK; kk += 32) {
      short8 af[4], bfb[4];
#pragma unroll
      for (int i = 0; i < 4; i++)
        af[i] = *reinterpret_cast<const short8*>(&As[wm * 64 + i * 16 + l15][kk + klo]);
#pragma unroll
      for (int j = 0; j < 4; j++)
        bfb[j] = *reinterpret_cast<const short8*>(&Bs[wn * 64 + j * 16 + l15][kk + klo]);
#pragma unroll
      for (int i = 0; i < 4; i++)
#pragma unroll
        for (int j = 0; j < 4; j++)
          acc[i][j] = mfma16(af[i], bfb[j], acc[i][j]);
    }
    __syncthreads();
  }
  int lg4 = (lane >> 4) * 4;
#pragma unroll
  for (int i = 0; i < 4; i++) {
#pragma unroll
    for (int j = 0; j < 4; j++) {
      int n = bn * GBN + wn * 64 + j * 16 + l15;
      float bv = bias[n];
#pragma unroll
      for (int r = 0; r < 4; r++) {
        int m = bm * GBM + wm * 64 + i * 16 + lg4 + r;
        C[(size_t)m * Ndim + n] = f2bf(acc[i][j][r] + bv);
      }
    }
  }
}

// ---------------- recurrent layer: 64 WGs (32/dir), K-split waves -----------
// Wave w = K-slice [w*128,(w+1)*128): spins on ITS 8 producers only, own
// acquire, no post-spin barrier. Plain h stores (L2-dirty; release wbl2
// publishes to LLC). xq prefetch issued after release (overlaps next spin).
__global__ __launch_bounds__(256, 1) void k_lstm5(const u16* __restrict__ xp,
                                                  const u16* __restrict__ whh_hi,
                                                  const u16* __restrict__ whh_lo,
                                                  u16* __restrict__ Yhi,
                                                  u16* __restrict__ Ylo,
                                                  int* __restrict__ flags) {
  int blk = blockIdx.x;
  int dir = blk >> 5, slice = blk & 31;
  int tid = threadIdx.x, wave = tid >> 6, lane = tid & 63;
  int u0 = slice * 16;
  int l15 = lane & 15, lg = lane >> 4;
  int klo = lg * 8;

  // Weight fragments: [gate ct][kt], K-cols wave*128 + kt*32 + klo .. +7
  f32x4 whf[4][4], wlf[4][4];
#pragma unroll
  for (int ct = 0; ct < 4; ct++) {
    size_t wr = ((size_t)dir * G4 + ct * HID + u0 + l15) * HID + wave * 128 + klo;
#pragma unroll
    for (int kt = 0; kt < 4; kt++) {
      whf[ct][kt] = *reinterpret_cast<const f32x4*>(whh_hi + wr + kt * 32);
      wlf[ct][kt] = *reinterpret_cast<const f32x4*>(whh_lo + wr + kt * 32);
    }
  }
#pragma unroll
  for (int ct = 0; ct < 4; ct++)
#pragma unroll
    for (int kt = 0; kt < 4; kt++) {
      asm volatile("" : "+v"(whf[ct][kt]));
      asm volatile("" : "+v"(wlf[ct][kt]));
    }

  __shared__ float pgx[4][NB][16][4];  // [gate][b][uu][wave] partials, 32 KB
  float cst[2] = {0.f, 0.f};
  int* myflags = flags + dir * T_SEQ * WPD;  // [s][wg]
  int bj[2], uj[2];
#pragma unroll
  for (int j = 0; j < 2; j++) {
    int p = tid + 256 * j;
    uj[j] = p & 15;
    bj[j] = p >> 4;
  }

  float xq[2][4];
  auto ldxq = [&](int row) {
#pragma unroll
    for (int j = 0; j < 2; j++) {
      const u16* xb = xp + (size_t)(row * NB + bj[j]) * XPW + dir * 2048 + u0 + uj[j];
#pragma unroll
      for (int g = 0; g < 4; g++) xq[j][g] = bf2f(xb[g * HID]);
    }
  };
  ldxq(dir ? (T_SEQ - 1) : 0);  // prologue prefetch for s=0

  for (int s = 0; s < T_SEQ; s++) {
    int trow = dir ? (T_SEQ - 1 - s) : s;
    if (s > 0) {
      // per-wave spin: only MY 8 producers (slices 8w..8w+7)
      int* slot = myflags + (s - 1) * WPD + wave * 8 + (lane & 7);
      int v;
      do {
        v = __hip_atomic_load(slot, __ATOMIC_RELAXED, __HIP_MEMORY_SCOPE_AGENT);
        if (__all(v != 0)) break;
        __builtin_amdgcn_s_sleep(1);
      } while (1);
      if (lane == 0)  // wave-level acquire: inv precedes h loads in prog order
        (void)__hip_atomic_load(myflags + (s - 1) * WPD + wave * 8,
                                __ATOMIC_ACQUIRE, __HIP_MEMORY_SCOPE_AGENT);
      int prow = dir ? (T_SEQ - s) : (s - 1);
      const u16* yb  = Yhi + ((size_t)prow * NB + l15) * 1024 + dir * HID + wave * 128 + klo;
      const u16* ybl = Ylo + ((size_t)prow * NB + l15) * 1024 + dir * HID + wave * 128 + klo;
      short8 ah[2][4], al[2][4];
#pragma unroll
      for (int mt = 0; mt < 2; mt++)
#pragma unroll
        for (int kt = 0; kt < 4; kt++) {
          ah[mt][kt] = *reinterpret_cast<const short8*>(yb + mt * 16 * 1024 + kt * 32);
          al[mt][kt] = *reinterpret_cast<const short8*>(ybl + mt * 16 * 1024 + kt * 32);
        }
      f32x4 accM[2][4], accC[2][4];
#pragma unroll
      for (int mt = 0; mt < 2; mt++)
#pragma unroll
        for (int ct = 0; ct < 4; ct++) {
          accM[mt][ct] = (f32x4){0.f, 0.f, 0.f, 0.f};
          accC[mt][ct] = (f32x4){0.f, 0.f, 0.f, 0.f};
        }
#pragma unroll
      for (int kt = 0; kt < 4; kt++)
#pragma unroll
        for (int mt = 0; mt < 2; mt++)
#pragma unroll
          for (int ct = 0; ct < 4; ct++) {
            short8 wh = __builtin_bit_cast(short8, whf[ct][kt]);
            short8 wl = __builtin_bit_cast(short8, wlf[ct][kt]);
            accM[mt][ct] = mfma16(ah[mt][kt], wh, accM[mt][ct]);
            accC[mt][ct] = mfma16(al[mt][kt], wh, accC[mt][ct]);
            accC[mt][ct] = mfma16(ah[mt][kt], wl, accC[mt][ct]);
          }
#pragma unroll
      for (int mt = 0; mt < 2; mt++)
#pragma unroll
        for (int ct = 0; ct < 4; ct++) {
          f32x4 v = accM[mt][ct] + accC[mt][ct];
#pragma unroll
          for (int r = 0; r < 4; r++)
            pgx[ct][mt * 16 + lg * 4 + r][l15][wave] = v[r];
        }
    }
    __syncthreads();
    // reduce partials + elementwise + h store (plain stores -> L2 dirty)
#pragma unroll
    for (int j = 0; j < 2; j++) {
      int b = bj[j], uu = uj[j];
      float gs[4];
#pragma unroll
      for (int g = 0; g < 4; g++) {
        float v = xq[j][g];
        if (s > 0) {
          float4 q = *reinterpret_cast<const float4*>(&pgx[g][b][uu][0]);
          v += (q.x + q.y) + (q.z + q.w);
        }
        gs[g] = v;
      }
      float iv = 1.f / (1.f + __expf(-gs[0]));
      float fv = 1.f / (1.f + __expf(-gs[1]));
      float gv = tanhf(gs[2]);
      float ov = 1.f / (1.f + __expf(-gs[3]));
      float c = fv * cst[j] + iv * gv;
      cst[j] = c;
      float h = ov * tanhf(c);
      u16 hh = f2bf(h);
      u16 hl = f2bf(h - bf2f(hh));
      size_t yo = ((size_t)trow * NB + b) * 1024 + dir * HID + u0 + uu;
      Yhi[yo] = hh;
      Ylo[yo] = hl;
    }
    __syncthreads();  // drains h stores (vmcnt0 before barrier)
    if (tid == 0)
      __hip_atomic_store(myflags + s * WPD + slice, 1, __ATOMIC_RELEASE,
                         __HIP_MEMORY_SCOPE_AGENT);
    if (s + 1 < T_SEQ)  // prefetch next xq AFTER release: overlaps next spin
      ldxq(dir ? (T_SEQ - 2 - s) : (s + 1));
  }
}

// ---------------- final pooled dot ------------------------------------------
__global__ void k_out(const u16* __restrict__ Yhi, const u16* __restrict__ Ylo,
                      const float* __restrict__ wout, const float* __restrict__ bout,
                      float* __restrict__ out) {
  int b = blockIdx.x;
  __shared__ float red[256];
  float s = 0.f;
  for (int c = threadIdx.x; c < 1024; c += 256) {
    size_t row = (c < 512) ? ((size_t)(T_SEQ - 1) * NB + b) : (size_t)b;
    float h = bf2f(Yhi[row * 1024 + c]) + bf2f(Ylo[row * 1024 + c]);
    s += h * wout[c];
  }
  red[threadIdx.x] = s;
  __syncthreads();
  for (int st = 128; st > 0; st >>= 1) {
    if (threadIdx.x < st) red[threadIdx.x] += red[threadIdx.x + st];
    __syncthreads();
  }
  if (threadIdx.x == 0) out[b] = red[0] + bout[0];
}

extern "C" void kernel_launch(void* const* d_in, const int* in_sizes, int n_in,
                              void* d_out, int out_size, void* d_ws, size_t ws_size,
                              hipStream_t stream) {
  const int*   inp  = (const int*)d_in[0];
  const float* emb  = (const float*)d_in[1];
  const float* Wih  = (const float*)d_in[2];
  const float* Whh  = (const float*)d_in[3];
  const float* bih  = (const float*)d_in[4];
  const float* bhh  = (const float*)d_in[5];
  const float* Wout = (const float*)d_in[6];
  const float* bout = (const float*)d_in[7];
  float* out = (float*)d_out;
  char* ws = (char*)d_ws;

  const size_t SZ_XP  = (size_t)NROWS * XPW * 2;
  const size_t SZ_Y   = (size_t)NROWS * 1024 * 2;
  const size_t SZ_WIH = (size_t)2 * 4096 * 1024 * 2;
  const size_t SZ_WHH = (size_t)2 * 2 * G4 * HID * 2;
  const size_t SZ_FLG = (size_t)2 * 2 * T_SEQ * WPD * sizeof(int);  // 256KB
  size_t off = 0;
  auto alloc = [&](size_t n) { size_t o = off; off += (n + 255) & ~(size_t)255; return o; };
  size_t o_xp   = alloc(SZ_XP);
  size_t o_y1h  = alloc(SZ_Y);
  size_t o_y1l  = alloc(SZ_Y);
  size_t o_y2h  = alloc(SZ_Y);   // aliased as X1 (embedding) before layer 2
  size_t o_y2l  = alloc(SZ_Y);
  size_t o_wih  = alloc(SZ_WIH);
  size_t o_whhh = alloc(SZ_WHH);
  size_t o_whhl = alloc(SZ_WHH);
  size_t o_bc   = alloc(2 * 4096 * sizeof(float));
  size_t o_flg  = alloc(SZ_FLG);
  if (ws_size < off) return;

  u16* xp   = (u16*)(ws + o_xp);
  u16* y1h  = (u16*)(ws + o_y1h);
  u16* y1l  = (u16*)(ws + o_y1l);
  u16* y2h  = (u16*)(ws + o_y2h);
  u16* y2l  = (u16*)(ws + o_y2l);
  u16* x1   = y2h;  // alias: dead before k_lstm5 layer-2 writes y2h
  u16* wihb = (u16*)(ws + o_wih);
  u16* whhh = (u16*)(ws + o_whhh);
  u16* whhl = (u16*)(ws + o_whhl);
  float* bc = (float*)(ws + o_bc);
  int* flg  = (int*)(ws + o_flg);

  hipMemsetAsync(flg, 0, SZ_FLG, stream);
  k_prep<<<4096, 256, 0, stream>>>(Wih, Whh, bih, bhh, wihb, whhh, whhl, bc);
  k_gather<<<NROWS, 256, 0, stream>>>(inp, emb, x1);
  k_gemm<<<dim3(NROWS / GBM, XPW / GBN), 256, 0, stream>>>(x1, wihb, bc, xp);
  k_lstm5<<<2 * WPD, 256, 0, stream>>>(xp, whhh, whhl, y1h, y1l, flg);
  k_gemm<<<dim3(NROWS / GBM, XPW / GBN), 256, 0, stream>>>(
      y1h, wihb + (size_t)4096 * 1024, bc + 4096, xp);
  k_lstm5<<<2 * WPD, 256, 0, stream>>>(xp, whhh + (size_t)2 * G4 * HID,
                                       whhl + (size_t)2 * G4 * HID, y2h, y2l,
                                       flg + 2 * T_SEQ * WPD);
  k_out<<<NB, 256, 0, stream>>>(y2h, y2l, Wout, bout, out);
}

// Round 6
// 5816.000 us; speedup vs baseline: 1.4213x; 1.4213x over previous
//
#include <hip/hip_runtime.h>
#include <stdint.h>

typedef unsigned short u16;
typedef unsigned int u32;
typedef __attribute__((ext_vector_type(8))) short short8;
typedef __attribute__((ext_vector_type(4))) float f32x4;

#define T_SEQ 512
#define NB 32
#define EMBD 1024
#define HID 512
#define G4 2048
#define NROWS (T_SEQ * NB)  // 16384
#define XPW 4096
#define WPD 32  // workgroups per direction

static __device__ __forceinline__ u16 f2bf(float x) {
  unsigned u = __float_as_uint(x);
  u += 0x7fffu + ((u >> 16) & 1u);
  return (u16)(u >> 16);
}
static __device__ __forceinline__ float bf2f(u16 b) {
  return __uint_as_float(((unsigned)b) << 16);
}
static __device__ __forceinline__ f32x4 mfma16(short8 a, short8 b, f32x4 c) {
  return __builtin_amdgcn_mfma_f32_16x16x32_bf16(a, b, c, 0, 0, 0);
}

// ---------------- weight prep: bf16 convert, Whh split hi/lo, bias merge ----
__global__ void k_prep(const float* __restrict__ Wih, const float* __restrict__ Whh,
                       const float* __restrict__ bih, const float* __restrict__ bhh,
                       u16* __restrict__ wih_b, u16* __restrict__ whh_hi,
                       u16* __restrict__ whh_lo, float* __restrict__ bcat) {
  size_t stride = (size_t)gridDim.x * blockDim.x;
  size_t i0 = (size_t)blockIdx.x * blockDim.x + threadIdx.x;
  const size_t n_ih = (size_t)2 * 2 * G4 * EMBD;  // [l][d][4H][E]
  for (size_t i = i0; i < n_ih; i += stride) wih_b[i] = f2bf(Wih[i]);
  const size_t n_hh = (size_t)2 * 2 * G4 * HID;   // [l][d][4H][H]
  for (size_t i = i0; i < n_hh; i += stride) {
    float w = Whh[i];
    u16 hi = f2bf(w);
    whh_hi[i] = hi;
    whh_lo[i] = f2bf(w - bf2f(hi));
  }
  for (size_t i = i0; i < 2 * 4096; i += stride) {
    size_t l = i >> 12, col = i & 4095;  // col = d*2048+g*512+u
    bcat[i] = bih[l * 4096 + col] + bhh[l * 4096 + col];
  }
}

// ---------------- embedding gather -> bf16 X [T*B, 1024] --------------------
__global__ void k_gather(const int* __restrict__ inp, const float* __restrict__ emb,
                         u16* __restrict__ X) {
  int row = blockIdx.x;  // t*32 + b
  int t = row >> 5, b = row & 31;
  int tok = inp[b * T_SEQ + t];
  const float* src = emb + (size_t)tok * EMBD + threadIdx.x * 4;
  float4 v = *reinterpret_cast<const float4*>(src);
  ushort4 o;
  o.x = f2bf(v.x); o.y = f2bf(v.y); o.z = f2bf(v.z); o.w = f2bf(v.w);
  *reinterpret_cast<ushort4*>(X + (size_t)row * EMBD + threadIdx.x * 4) = o;
}

// ---------------- xp GEMM: C[M,4096] = A[M,1024] @ B[4096,1024]^T + bias ----
#define GBM 128
#define GBN 128
#define GBK 64
__global__ __launch_bounds__(256) void k_gemm(const u16* __restrict__ A,
                                              const u16* __restrict__ B,
                                              const float* __restrict__ bias,
                                              u16* __restrict__ C) {
  __shared__ u16 As[GBM][GBK];
  __shared__ u16 Bs[GBN][GBK];
  const int Kdim = 1024, Ndim = 4096;
  int bm = blockIdx.x, bn = blockIdx.y;
  int tid = threadIdx.x;
  int lane = tid & 63, wave = tid >> 6;
  int wm = wave >> 1, wn = wave & 1;
  int l15 = lane & 15, klo = (lane >> 4) * 8;
  f32x4 acc[4][4] = {};
  for (int k0 = 0; k0 < Kdim; k0 += GBK) {
#pragma unroll
    for (int s = 0; s < 4; s++) {
      int seg = tid + s * 256;
      int r = seg >> 3, cs = (seg & 7) * 8;
      *reinterpret_cast<short8*>(&As[r][cs]) =
          *reinterpret_cast<const short8*>(A + (size_t)(bm * GBM + r) * Kdim + k0 + cs);
      *reinterpret_cast<short8*>(&Bs[r][cs]) =
          *reinterpret_cast<const short8*>(B + (size_t)(bn * GBN + r) * Kdim + k0 + cs);
    }
    __syncthreads();
#pragma unroll
    for (int kk = 0; kk < GBK; kk += 32) {
      short8 af[4], bfb[4];
#pragma unroll
      for (int i = 0; i < 4; i++)
        af[i] = *reinterpret_cast<const short8*>(&As[wm * 64 + i * 16 + l15][kk + klo]);
#pragma unroll
      for (int j = 0; j < 4; j++)
        bfb[j] = *reinterpret_cast<const short8*>(&Bs[wn * 64 + j * 16 + l15][kk + klo]);
#pragma unroll
      for (int i = 0; i < 4; i++)
#pragma unroll
        for (int j = 0; j < 4; j++)
          acc[i][j] = mfma16(af[i], bfb[j], acc[i][j]);
    }
    __syncthreads();
  }
  int lg4 = (lane >> 4) * 4;
#pragma unroll
  for (int i = 0; i < 4; i++) {
#pragma unroll
    for (int j = 0; j < 4; j++) {
      int n = bn * GBN + wn * 64 + j * 16 + l15;
      float bv = bias[n];
#pragma unroll
      for (int r = 0; r < 4; r++) {
        int m = bm * GBM + wm * 64 + i * 16 + lg4 + r;
        C[(size_t)m * Ndim + n] = f2bf(acc[i][j][r] + bv);
      }
    }
  }
}

// ---------------- recurrent layer: 64 WGs (32/dir), K-split waves -----------
// Protocol v3: h packed (hi<<16|lo) stored via RELAXED agent atomics (SC1 ->
// LLC direct, no dirty L2). syncthreads drains vmcnt; flag store RELAXED
// agent atomic (no wbl2). Consumers: relaxed per-wave spin + workgroup
// acquire fence (no L2 inv -- h lines are first-touch per XCD per step).
__global__ __launch_bounds__(256, 1) void k_lstm6(const u16* __restrict__ xp,
                                                  const u16* __restrict__ whh_hi,
                                                  const u16* __restrict__ whh_lo,
                                                  u32* __restrict__ ypk,
                                                  u16* __restrict__ yh,
                                                  int* __restrict__ flags,
                                                  int write_yh) {
  int blk = blockIdx.x;
  int dir = blk >> 5, slice = blk & 31;
  int tid = threadIdx.x, wave = tid >> 6, lane = tid & 63;
  int u0 = slice * 16;
  int l15 = lane & 15, lg = lane >> 4;
  int klo = lg * 8;

  // Weight fragments: [gate ct][kt], K-cols wave*128 + kt*32 + klo .. +7
  f32x4 whf[4][4], wlf[4][4];
#pragma unroll
  for (int ct = 0; ct < 4; ct++) {
    size_t wr = ((size_t)dir * G4 + ct * HID + u0 + l15) * HID + wave * 128 + klo;
#pragma unroll
    for (int kt = 0; kt < 4; kt++) {
      whf[ct][kt] = *reinterpret_cast<const f32x4*>(whh_hi + wr + kt * 32);
      wlf[ct][kt] = *reinterpret_cast<const f32x4*>(whh_lo + wr + kt * 32);
    }
  }
#pragma unroll
  for (int ct = 0; ct < 4; ct++)
#pragma unroll
    for (int kt = 0; kt < 4; kt++) {
      asm volatile("" : "+v"(whf[ct][kt]));
      asm volatile("" : "+v"(wlf[ct][kt]));
    }

  __shared__ float pgx[4][NB][16][4];  // [gate][b][uu][wave] partials, 32 KB
  float cst[2] = {0.f, 0.f};
  int* myflags = flags + dir * T_SEQ * WPD;  // [s][wg]
  int bj[2], uj[2];
#pragma unroll
  for (int j = 0; j < 2; j++) {
    int p = tid + 256 * j;
    uj[j] = p & 15;
    bj[j] = p >> 4;
  }

  float xq[2][4];
  auto ldxq = [&](int row) {
#pragma unroll
    for (int j = 0; j < 2; j++) {
      const u16* xb = xp + (size_t)(row * NB + bj[j]) * XPW + dir * 2048 + u0 + uj[j];
#pragma unroll
      for (int g = 0; g < 4; g++) xq[j][g] = bf2f(xb[g * HID]);
    }
  };
  ldxq(dir ? (T_SEQ - 1) : 0);  // prologue prefetch for s=0

  for (int s = 0; s < T_SEQ; s++) {
    int trow = dir ? (T_SEQ - 1 - s) : s;
    if (s > 0) {
      // per-wave spin: only MY 8 producers (slices 8w..8w+7), relaxed
      int* slot = myflags + (s - 1) * WPD + wave * 8 + (lane & 7);
      int v;
      do {
        v = __hip_atomic_load(slot, __ATOMIC_RELAXED, __HIP_MEMORY_SCOPE_AGENT);
        if (__all(v != 0)) break;
        __builtin_amdgcn_s_sleep(1);
      } while (1);
      // compiler/waitcnt fence only -- NO L2 invalidate
      __builtin_amdgcn_fence(__ATOMIC_ACQUIRE, "workgroup");
      int prow = dir ? (T_SEQ - s) : (s - 1);
      const u32* yb = ypk + ((size_t)prow * NB + l15) * 1024 + dir * HID + wave * 128 + klo;
      short8 ah[2][4], al[2][4];
#pragma unroll
      for (int mt = 0; mt < 2; mt++) {
        const u32* yr = yb + (size_t)mt * 16 * 1024;
#pragma unroll
        for (int kt = 0; kt < 4; kt++) {
          const uint4* p = reinterpret_cast<const uint4*>(yr + kt * 32);
          uint4 a = p[0], b = p[1];
          u32 v8[8] = {a.x, a.y, a.z, a.w, b.x, b.y, b.z, b.w};
          union { short8 s8; u32 u[4]; } uh, ul;
#pragma unroll
          for (int i = 0; i < 4; i++) {
            uh.u[i] = (v8[2 * i + 1] & 0xFFFF0000u) | (v8[2 * i] >> 16);
            ul.u[i] = (v8[2 * i + 1] << 16) | (v8[2 * i] & 0xFFFFu);
          }
          ah[mt][kt] = uh.s8;
          al[mt][kt] = ul.s8;
        }
      }
      f32x4 accM[2][4], accC[2][4];
#pragma unroll
      for (int mt = 0; mt < 2; mt++)
#pragma unroll
        for (int ct = 0; ct < 4; ct++) {
          accM[mt][ct] = (f32x4){0.f, 0.f, 0.f, 0.f};
          accC[mt][ct] = (f32x4){0.f, 0.f, 0.f, 0.f};
        }
#pragma unroll
      for (int kt = 0; kt < 4; kt++)
#pragma unroll
        for (int mt = 0; mt < 2; mt++)
#pragma unroll
          for (int ct = 0; ct < 4; ct++) {
            short8 wh = __builtin_bit_cast(short8, whf[ct][kt]);
            short8 wl = __builtin_bit_cast(short8, wlf[ct][kt]);
            accM[mt][ct] = mfma16(ah[mt][kt], wh, accM[mt][ct]);
            accC[mt][ct] = mfma16(al[mt][kt], wh, accC[mt][ct]);
            accC[mt][ct] = mfma16(ah[mt][kt], wl, accC[mt][ct]);
          }
#pragma unroll
      for (int mt = 0; mt < 2; mt++)
#pragma unroll
        for (int ct = 0; ct < 4; ct++) {
          f32x4 v4 = accM[mt][ct] + accC[mt][ct];
#pragma unroll
          for (int r = 0; r < 4; r++)
            pgx[ct][mt * 16 + lg * 4 + r][l15][wave] = v4[r];
        }
    }
    __syncthreads();
    // reduce partials + elementwise + packed h store (SC1 -> LLC)
#pragma unroll
    for (int j = 0; j < 2; j++) {
      int b = bj[j], uu = uj[j];
      float gs[4];
#pragma unroll
      for (int g = 0; g < 4; g++) {
        float v = xq[j][g];
        if (s > 0) {
          float4 q = *reinterpret_cast<const float4*>(&pgx[g][b][uu][0]);
          v += (q.x + q.y) + (q.z + q.w);
        }
        gs[g] = v;
      }
      float iv = 1.f / (1.f + __expf(-gs[0]));
      float fv = 1.f / (1.f + __expf(-gs[1]));
      float gv = tanhf(gs[2]);
      float ov = 1.f / (1.f + __expf(-gs[3]));
      float c = fv * cst[j] + iv * gv;
      cst[j] = c;
      float h = ov * tanhf(c);
      u16 hh = f2bf(h);
      u16 hl = f2bf(h - bf2f(hh));
      size_t yo = ((size_t)trow * NB + b) * 1024 + dir * HID + u0 + uu;
      __hip_atomic_store(ypk + yo, ((u32)hh << 16) | hl, __ATOMIC_RELAXED,
                         __HIP_MEMORY_SCOPE_AGENT);
      if (write_yh) yh[yo] = hh;  // cross-kernel only (end-of-dispatch flush)
    }
    __syncthreads();  // vmcnt(0) per wave: all SC1 h-stores acked at LLC
    if (tid == 0)     // relaxed flag store: no wbl2
      __hip_atomic_store(myflags + s * WPD + slice, 1, __ATOMIC_RELAXED,
                         __HIP_MEMORY_SCOPE_AGENT);
    if (s + 1 < T_SEQ)  // prefetch next xq AFTER flag: overlaps next spin
      ldxq(dir ? (T_SEQ - 2 - s) : (s + 1));
  }
}

// ---------------- final pooled dot ------------------------------------------
__global__ void k_out(const u32* __restrict__ ypk, const float* __restrict__ wout,
                      const float* __restrict__ bout, float* __restrict__ out) {
  int b = blockIdx.x;
  __shared__ float red[256];
  float s = 0.f;
  for (int c = threadIdx.x; c < 1024; c += 256) {
    size_t row = (c < 512) ? ((size_t)(T_SEQ - 1) * NB + b) : (size_t)b;
    u32 pk = ypk[row * 1024 + c];
    float h = bf2f((u16)(pk >> 16)) + bf2f((u16)(pk & 0xFFFFu));
    s += h * wout[c];
  }
  red[threadIdx.x] = s;
  __syncthreads();
  for (int st = 128; st > 0; st >>= 1) {
    if (threadIdx.x < st) red[threadIdx.x] += red[threadIdx.x + st];
    __syncthreads();
  }
  if (threadIdx.x == 0) out[b] = red[0] + bout[0];
}

extern "C" void kernel_launch(void* const* d_in, const int* in_sizes, int n_in,
                              void* d_out, int out_size, void* d_ws, size_t ws_size,
                              hipStream_t stream) {
  const int*   inp  = (const int*)d_in[0];
  const float* emb  = (const float*)d_in[1];
  const float* Wih  = (const float*)d_in[2];
  const float* Whh  = (const float*)d_in[3];
  const float* bih  = (const float*)d_in[4];
  const float* bhh  = (const float*)d_in[5];
  const float* Wout = (const float*)d_in[6];
  const float* bout = (const float*)d_in[7];
  float* out = (float*)d_out;
  char* ws = (char*)d_ws;

  const size_t SZ_XP  = (size_t)NROWS * XPW * 2;       // 134 MB
  const size_t SZ_YPK = (size_t)NROWS * 1024 * 4;      // 67 MB
  const size_t SZ_YH  = (size_t)NROWS * 1024 * 2;      // 33.5 MB
  const size_t SZ_WIH = (size_t)2 * 4096 * 1024 * 2;
  const size_t SZ_WHH = (size_t)2 * 2 * G4 * HID * 2;
  const size_t SZ_FLG = (size_t)2 * 2 * T_SEQ * WPD * sizeof(int);  // 256KB
  size_t off = 0;
  auto alloc = [&](size_t n) { size_t o = off; off += (n + 255) & ~(size_t)255; return o; };
  size_t o_xp   = alloc(SZ_XP);
  size_t o_ypk  = alloc(SZ_YPK);
  size_t o_y1h  = alloc(SZ_YH);
  size_t o_x1   = alloc(SZ_YH);
  size_t o_wih  = alloc(SZ_WIH);
  size_t o_whhh = alloc(SZ_WHH);
  size_t o_whhl = alloc(SZ_WHH);
  size_t o_bc   = alloc(2 * 4096 * sizeof(float));
  size_t o_flg  = alloc(SZ_FLG);
  if (ws_size < off) return;

  u16* xp   = (u16*)(ws + o_xp);
  u32* ypk  = (u32*)(ws + o_ypk);
  u16* y1h  = (u16*)(ws + o_y1h);
  u16* x1   = (u16*)(ws + o_x1);
  u16* wihb = (u16*)(ws + o_wih);
  u16* whhh = (u16*)(ws + o_whhh);
  u16* whhl = (u16*)(ws + o_whhl);
  float* bc = (float*)(ws + o_bc);
  int* flg  = (int*)(ws + o_flg);

  hipMemsetAsync(flg, 0, SZ_FLG, stream);
  k_prep<<<4096, 256, 0, stream>>>(Wih, Whh, bih, bhh, wihb, whhh, whhl, bc);
  k_gather<<<NROWS, 256, 0, stream>>>(inp, emb, x1);
  k_gemm<<<dim3(NROWS / GBM, XPW / GBN), 256, 0, stream>>>(x1, wihb, bc, xp);
  k_lstm6<<<2 * WPD, 256, 0, stream>>>(xp, whhh, whhl, ypk, y1h, flg, 1);
  k_gemm<<<dim3(NROWS / GBM, XPW / GBN), 256, 0, stream>>>(
      y1h, wihb + (size_t)4096 * 1024, bc + 4096, xp);
  k_lstm6<<<2 * WPD, 256, 0, stream>>>(xp, whhh + (size_t)2 * G4 * HID,
                                       whhl + (size_t)2 * G4 * HID, ypk, y1h,
                                       flg + 2 * T_SEQ * WPD, 0);
  k_out<<<NB, 256, 0, stream>>>(ypk, Wout, bout, out);
}

// Round 7
// 5463.806 us; speedup vs baseline: 1.5130x; 1.0645x over previous
//
#include <hip/hip_runtime.h>
#include <stdint.h>

typedef unsigned short u16;
typedef unsigned int u32;
typedef __attribute__((ext_vector_type(8))) short short8;
typedef __attribute__((ext_vector_type(4))) float f32x4;

#define T_SEQ 512
#define NB 32
#define EMBD 1024
#define HID 512
#define G4 2048
#define NROWS (T_SEQ * NB)  // 16384
#define XPW 4096
#define WPD 32  // workgroups per direction

static __device__ __forceinline__ u16 f2bf(float x) {
  unsigned u = __float_as_uint(x);
  u += 0x7fffu + ((u >> 16) & 1u);
  return (u16)(u >> 16);
}
static __device__ __forceinline__ float bf2f(u16 b) {
  return __uint_as_float(((unsigned)b) << 16);
}
static __device__ __forceinline__ f32x4 mfma16(short8 a, short8 b, f32x4 c) {
  return __builtin_amdgcn_mfma_f32_16x16x32_bf16(a, b, c, 0, 0, 0);
}
static __device__ __forceinline__ float fast_tanh(float x) {
  float e = __expf(2.f * x);
  return 1.f - 2.f / (e + 1.f);
}
static __device__ __forceinline__ float sigm(float x) {
  return 1.f / (1.f + __expf(-x));
}

// ---------------- weight prep: bf16 convert, Whh split hi/lo, bias merge ----
__global__ void k_prep(const float* __restrict__ Wih, const float* __restrict__ Whh,
                       const float* __restrict__ bih, const float* __restrict__ bhh,
                       u16* __restrict__ wih_b, u16* __restrict__ whh_hi,
                       u16* __restrict__ whh_lo, float* __restrict__ bcat) {
  size_t stride = (size_t)gridDim.x * blockDim.x;
  size_t i0 = (size_t)blockIdx.x * blockDim.x + threadIdx.x;
  const size_t n_ih = (size_t)2 * 2 * G4 * EMBD;  // [l][d][4H][E]
  for (size_t i = i0; i < n_ih; i += stride) wih_b[i] = f2bf(Wih[i]);
  const size_t n_hh = (size_t)2 * 2 * G4 * HID;   // [l][d][4H][H]
  for (size_t i = i0; i < n_hh; i += stride) {
    float w = Whh[i];
    u16 hi = f2bf(w);
    whh_hi[i] = hi;
    whh_lo[i] = f2bf(w - bf2f(hi));
  }
  for (size_t i = i0; i < 2 * 4096; i += stride) {
    size_t l = i >> 12, col = i & 4095;  // col = d*2048+g*512+u
    bcat[i] = bih[l * 4096 + col] + bhh[l * 4096 + col];
  }
}

// ---------------- embedding gather -> bf16 X [T*B, 1024] --------------------
__global__ void k_gather(const int* __restrict__ inp, const float* __restrict__ emb,
                         u16* __restrict__ X) {
  int row = blockIdx.x;  // t*32 + b
  int t = row >> 5, b = row & 31;
  int tok = inp[b * T_SEQ + t];
  const float* src = emb + (size_t)tok * EMBD + threadIdx.x * 4;
  float4 v = *reinterpret_cast<const float4*>(src);
  ushort4 o;
  o.x = f2bf(v.x); o.y = f2bf(v.y); o.z = f2bf(v.z); o.w = f2bf(v.w);
  *reinterpret_cast<ushort4*>(X + (size_t)row * EMBD + threadIdx.x * 4) = o;
}

// ---------------- xp GEMM: C[M,4096] = A[M,1024] @ B[4096,1024]^T + bias ----
#define GBM 128
#define GBN 128
#define GBK 64
__global__ __launch_bounds__(256) void k_gemm(const u16* __restrict__ A,
                                              const u16* __restrict__ B,
                                              const float* __restrict__ bias,
                                              u16* __restrict__ C) {
  __shared__ u16 As[GBM][GBK];
  __shared__ u16 Bs[GBN][GBK];
  const int Kdim = 1024, Ndim = 4096;
  int bm = blockIdx.x, bn = blockIdx.y;
  int tid = threadIdx.x;
  int lane = tid & 63, wave = tid >> 6;
  int wm = wave >> 1, wn = wave & 1;
  int l15 = lane & 15, klo = (lane >> 4) * 8;
  f32x4 acc[4][4] = {};
  for (int k0 = 0; k0 < Kdim; k0 += GBK) {
#pragma unroll
    for (int s = 0; s < 4; s++) {
      int seg = tid + s * 256;
      int r = seg >> 3, cs = (seg & 7) * 8;
      *reinterpret_cast<short8*>(&As[r][cs]) =
          *reinterpret_cast<const short8*>(A + (size_t)(bm * GBM + r) * Kdim + k0 + cs);
      *reinterpret_cast<short8*>(&Bs[r][cs]) =
          *reinterpret_cast<const short8*>(B + (size_t)(bn * GBN + r) * Kdim + k0 + cs);
    }
    __syncthreads();
#pragma unroll
    for (int kk = 0; kk < GBK; kk += 32) {
      short8 af[4], bfb[4];
#pragma unroll
      for (int i = 0; i < 4; i++)
        af[i] = *reinterpret_cast<const short8*>(&As[wm * 64 + i * 16 + l15][kk + klo]);
#pragma unroll
      for (int j = 0; j < 4; j++)
        bfb[j] = *reinterpret_cast<const short8*>(&Bs[wn * 64 + j * 16 + l15][kk + klo]);
#pragma unroll
      for (int i = 0; i < 4; i++)
#pragma unroll
        for (int j = 0; j < 4; j++)
          acc[i][j] = mfma16(af[i], bfb[j], acc[i][j]);
    }
    __syncthreads();
  }
  int lg4 = (lane >> 4) * 4;
#pragma unroll
  for (int i = 0; i < 4; i++) {
#pragma unroll
    for (int j = 0; j < 4; j++) {
      int n = bn * GBN + wn * 64 + j * 16 + l15;
      float bv = bias[n];
#pragma unroll
      for (int r = 0; r < 4; r++) {
        int m = bm * GBM + wm * 64 + i * 16 + lg4 + r;
        C[(size_t)m * Ndim + n] = f2bf(acc[i][j][r] + bv);
      }
    }
  }
}

// ---------------- recurrent layer: 64 WGs (32/dir), K-split waves -----------
// v4: xq force-consumed BEFORE spin (clean vmcnt in poll loop); pgx padded
// to 5 (conflict-free); v_perm unpack; fast tanh. Protocol as v3 (relaxed
// SC1 h-stores, relaxed flags, workgroup acquire fence).
__global__ __launch_bounds__(256, 1) void k_lstm7(const u16* __restrict__ xp,
                                                  const u16* __restrict__ whh_hi,
                                                  const u16* __restrict__ whh_lo,
                                                  u32* __restrict__ ypk,
                                                  u16* __restrict__ yh,
                                                  int* __restrict__ flags,
                                                  int write_yh) {
  int blk = blockIdx.x;
  int dir = blk >> 5, slice = blk & 31;
  int tid = threadIdx.x, wave = tid >> 6, lane = tid & 63;
  int u0 = slice * 16;
  int l15 = lane & 15, lg = lane >> 4;
  int klo = lg * 8;

  // Weight fragments: [gate ct][kt], K-cols wave*128 + kt*32 + klo .. +7
  f32x4 whf[4][4], wlf[4][4];
#pragma unroll
  for (int ct = 0; ct < 4; ct++) {
    size_t wr = ((size_t)dir * G4 + ct * HID + u0 + l15) * HID + wave * 128 + klo;
#pragma unroll
    for (int kt = 0; kt < 4; kt++) {
      whf[ct][kt] = *reinterpret_cast<const f32x4*>(whh_hi + wr + kt * 32);
      wlf[ct][kt] = *reinterpret_cast<const f32x4*>(whh_lo + wr + kt * 32);
    }
  }
#pragma unroll
  for (int ct = 0; ct < 4; ct++)
#pragma unroll
    for (int kt = 0; kt < 4; kt++) {
      asm volatile("" : "+v"(whf[ct][kt]));
      asm volatile("" : "+v"(wlf[ct][kt]));
    }

  __shared__ float pgx[4][NB][16][5];  // [gate][b][uu][wave+pad]: 5 % 32 free
  float cst[2] = {0.f, 0.f};
  int* myflags = flags + dir * T_SEQ * WPD;  // [s][wg]
  int bj[2], uj[2];
#pragma unroll
  for (int j = 0; j < 2; j++) {
    int p = tid + 256 * j;
    uj[j] = p & 15;
    bj[j] = p >> 4;
  }

  float xq[2][4];
  auto ldxq = [&](int row) {
#pragma unroll
    for (int j = 0; j < 2; j++) {
      const u16* xb = xp + (size_t)(row * NB + bj[j]) * XPW + dir * 2048 + u0 + uj[j];
#pragma unroll
      for (int g = 0; g < 4; g++) xq[j][g] = bf2f(xb[g * HID]);
    }
    // Force-consume now: keeps the poll loop's vmcnt clean (a dependent
    // s_waitcnt in the spin would otherwise wait on these HBM loads).
    asm volatile("s_waitcnt vmcnt(0)" ::: "memory");
  };
  ldxq(dir ? (T_SEQ - 1) : 0);  // prologue prefetch for s=0

  for (int s = 0; s < T_SEQ; s++) {
    int trow = dir ? (T_SEQ - 1 - s) : s;
    if (s > 0) {
      // per-wave spin: only MY 8 producers (slices 8w..8w+7), relaxed
      int* slot = myflags + (s - 1) * WPD + wave * 8 + (lane & 7);
      int v;
      do {
        v = __hip_atomic_load(slot, __ATOMIC_RELAXED, __HIP_MEMORY_SCOPE_AGENT);
        if (__all(v != 0)) break;
        __builtin_amdgcn_s_sleep(1);
      } while (1);
      // compiler/waitcnt fence only -- NO L2 invalidate
      __builtin_amdgcn_fence(__ATOMIC_ACQUIRE, "workgroup");
      int prow = dir ? (T_SEQ - s) : (s - 1);
      const u32* yb = ypk + ((size_t)prow * NB + l15) * 1024 + dir * HID + wave * 128 + klo;
      short8 ah[2][4], al[2][4];
#pragma unroll
      for (int mt = 0; mt < 2; mt++) {
        const u32* yr = yb + (size_t)mt * 16 * 1024;
#pragma unroll
        for (int kt = 0; kt < 4; kt++) {
          const uint4* p = reinterpret_cast<const uint4*>(yr + kt * 32);
          uint4 a = p[0], b = p[1];
          u32 v8[8] = {a.x, a.y, a.z, a.w, b.x, b.y, b.z, b.w};
          union { short8 s8; u32 u[4]; } uh, ul;
#pragma unroll
          for (int i = 0; i < 4; i++) {
            // [v1.hi, v0.hi] and [v1.lo, v0.lo] via single byte-perms
            uh.u[i] = __builtin_amdgcn_perm(v8[2 * i + 1], v8[2 * i], 0x07060302u);
            ul.u[i] = __builtin_amdgcn_perm(v8[2 * i + 1], v8[2 * i], 0x05040100u);
          }
          ah[mt][kt] = uh.s8;
          al[mt][kt] = ul.s8;
        }
      }
      f32x4 accM[2][4], accC[2][4];
#pragma unroll
      for (int mt = 0; mt < 2; mt++)
#pragma unroll
        for (int ct = 0; ct < 4; ct++) {
          accM[mt][ct] = (f32x4){0.f, 0.f, 0.f, 0.f};
          accC[mt][ct] = (f32x4){0.f, 0.f, 0.f, 0.f};
        }
#pragma unroll
      for (int kt = 0; kt < 4; kt++)
#pragma unroll
        for (int mt = 0; mt < 2; mt++)
#pragma unroll
          for (int ct = 0; ct < 4; ct++) {
            short8 wh = __builtin_bit_cast(short8, whf[ct][kt]);
            short8 wl = __builtin_bit_cast(short8, wlf[ct][kt]);
            accM[mt][ct] = mfma16(ah[mt][kt], wh, accM[mt][ct]);
            accC[mt][ct] = mfma16(al[mt][kt], wh, accC[mt][ct]);
            accC[mt][ct] = mfma16(ah[mt][kt], wl, accC[mt][ct]);
          }
#pragma unroll
      for (int mt = 0; mt < 2; mt++)
#pragma unroll
        for (int ct = 0; ct < 4; ct++) {
          f32x4 v4 = accM[mt][ct] + accC[mt][ct];
#pragma unroll
          for (int r = 0; r < 4; r++)
            pgx[ct][mt * 16 + lg * 4 + r][l15][wave] = v4[r];
        }
    }
    __syncthreads();
    // reduce partials + elementwise + packed h store (SC1 -> LLC)
#pragma unroll
    for (int j = 0; j < 2; j++) {
      int b = bj[j], uu = uj[j];
      float gs[4];
#pragma unroll
      for (int g = 0; g < 4; g++) {
        float v = xq[j][g];
        if (s > 0)
          v += (pgx[g][b][uu][0] + pgx[g][b][uu][1]) +
               (pgx[g][b][uu][2] + pgx[g][b][uu][3]);
        gs[g] = v;
      }
      float iv = sigm(gs[0]);
      float fv = sigm(gs[1]);
      float gv = fast_tanh(gs[2]);
      float ov = sigm(gs[3]);
      float c = fv * cst[j] + iv * gv;
      cst[j] = c;
      float h = ov * fast_tanh(c);
      u16 hh = f2bf(h);
      u16 hl = f2bf(h - bf2f(hh));
      size_t yo = ((size_t)trow * NB + b) * 1024 + dir * HID + u0 + uu;
      __hip_atomic_store(ypk + yo, ((u32)hh << 16) | hl, __ATOMIC_RELAXED,
                         __HIP_MEMORY_SCOPE_AGENT);
      if (write_yh) yh[yo] = hh;  // cross-kernel only (end-of-dispatch flush)
    }
    __syncthreads();  // vmcnt(0) per wave: all SC1 h-stores acked at LLC
    if (tid == 0)     // relaxed flag store: no wbl2
      __hip_atomic_store(myflags + s * WPD + slice, 1, __ATOMIC_RELAXED,
                         __HIP_MEMORY_SCOPE_AGENT);
    if (s + 1 < T_SEQ)  // prefetch + consume next xq: overlaps producers
      ldxq(dir ? (T_SEQ - 2 - s) : (s + 1));
  }
}

// ---------------- final pooled dot ------------------------------------------
__global__ void k_out(const u32* __restrict__ ypk, const float* __restrict__ wout,
                      const float* __restrict__ bout, float* __restrict__ out) {
  int b = blockIdx.x;
  __shared__ float red[256];
  float s = 0.f;
  for (int c = threadIdx.x; c < 1024; c += 256) {
    size_t row = (c < 512) ? ((size_t)(T_SEQ - 1) * NB + b) : (size_t)b;
    u32 pk = ypk[row * 1024 + c];
    float h = bf2f((u16)(pk >> 16)) + bf2f((u16)(pk & 0xFFFFu));
    s += h * wout[c];
  }
  red[threadIdx.x] = s;
  __syncthreads();
  for (int st = 128; st > 0; st >>= 1) {
    if (threadIdx.x < st) red[threadIdx.x] += red[threadIdx.x + st];
    __syncthreads();
  }
  if (threadIdx.x == 0) out[b] = red[0] + bout[0];
}

extern "C" void kernel_launch(void* const* d_in, const int* in_sizes, int n_in,
                              void* d_out, int out_size, void* d_ws, size_t ws_size,
                              hipStream_t stream) {
  const int*   inp  = (const int*)d_in[0];
  const float* emb  = (const float*)d_in[1];
  const float* Wih  = (const float*)d_in[2];
  const float* Whh  = (const float*)d_in[3];
  const float* bih  = (const float*)d_in[4];
  const float* bhh  = (const float*)d_in[5];
  const float* Wout = (const float*)d_in[6];
  const float* bout = (const float*)d_in[7];
  float* out = (float*)d_out;
  char* ws = (char*)d_ws;

  const size_t SZ_XP  = (size_t)NROWS * XPW * 2;       // 134 MB
  const size_t SZ_YPK = (size_t)NROWS * 1024 * 4;      // 67 MB
  const size_t SZ_YH  = (size_t)NROWS * 1024 * 2;      // 33.5 MB
  const size_t SZ_WIH = (size_t)2 * 4096 * 1024 * 2;
  const size_t SZ_WHH = (size_t)2 * 2 * G4 * HID * 2;
  const size_t SZ_FLG = (size_t)2 * 2 * T_SEQ * WPD * sizeof(int);  // 256KB
  size_t off = 0;
  auto alloc = [&](size_t n) { size_t o = off; off += (n + 255) & ~(size_t)255; return o; };
  size_t o_xp   = alloc(SZ_XP);
  size_t o_ypk  = alloc(SZ_YPK);
  size_t o_y1h  = alloc(SZ_YH);
  size_t o_x1   = alloc(SZ_YH);
  size_t o_wih  = alloc(SZ_WIH);
  size_t o_whhh = alloc(SZ_WHH);
  size_t o_whhl = alloc(SZ_WHH);
  size_t o_bc   = alloc(2 * 4096 * sizeof(float));
  size_t o_flg  = alloc(SZ_FLG);
  if (ws_size < off) return;

  u16* xp   = (u16*)(ws + o_xp);
  u32* ypk  = (u32*)(ws + o_ypk);
  u16* y1h  = (u16*)(ws + o_y1h);
  u16* x1   = (u16*)(ws + o_x1);
  u16* wihb = (u16*)(ws + o_wih);
  u16* whhh = (u16*)(ws + o_whhh);
  u16* whhl = (u16*)(ws + o_whhl);
  float* bc = (float*)(ws + o_bc);
  int* flg  = (int*)(ws + o_flg);

  hipMemsetAsync(flg, 0, SZ_FLG, stream);
  k_prep<<<4096, 256, 0, stream>>>(Wih, Whh, bih, bhh, wihb, whhh, whhl, bc);
  k_gather<<<NROWS, 256, 0, stream>>>(inp, emb, x1);
  k_gemm<<<dim3(NROWS / GBM, XPW / GBN), 256, 0, stream>>>(x1, wihb, bc, xp);
  k_lstm7<<<2 * WPD, 256, 0, stream>>>(xp, whhh, whhl, ypk, y1h, flg, 1);
  k_gemm<<<dim3(NROWS / GBM, XPW / GBN), 256, 0, stream>>>(
      y1h, wihb + (size_t)4096 * 1024, bc + 4096, xp);
  k_lstm7<<<2 * WPD, 256, 0, stream>>>(xp, whhh + (size_t)2 * G4 * HID,
                                       whhl + (size_t)2 * G4 * HID, ypk, y1h,
                                       flg + 2 * T_SEQ * WPD, 0);
  k_out<<<NB, 256, 0, stream>>>(ypk, Wout, bout, out);
}

// Round 8
// 5380.426 us; speedup vs baseline: 1.5364x; 1.0155x over previous
//
#include <hip/hip_runtime.h>
#include <stdint.h>

typedef unsigned short u16;
typedef unsigned int u32;
typedef __attribute__((ext_vector_type(8))) short short8;
typedef __attribute__((ext_vector_type(4))) float f32x4;

#define T_SEQ 512
#define NB 32
#define EMBD 1024
#define HID 512
#define G4 2048
#define NROWS (T_SEQ * NB)  // 16384
#define XPW 4096
#define WPD 32  // workgroups per direction
#define SENTW 0xFFFFFFFFu

static __device__ __forceinline__ u16 f2bf(float x) {
  unsigned u = __float_as_uint(x);
  u += 0x7fffu + ((u >> 16) & 1u);
  return (u16)(u >> 16);
}
static __device__ __forceinline__ float bf2f(u16 b) {
  return __uint_as_float(((unsigned)b) << 16);
}
static __device__ __forceinline__ f32x4 mfma16(short8 a, short8 b, f32x4 c) {
  return __builtin_amdgcn_mfma_f32_16x16x32_bf16(a, b, c, 0, 0, 0);
}
static __device__ __forceinline__ float fast_tanh(float x) {
  float e = __expf(2.f * x);
  return 1.f - 2.f / (e + 1.f);
}
static __device__ __forceinline__ float sigm(float x) {
  return 1.f / (1.f + __expf(-x));
}
static __device__ __forceinline__ void barrier_lds() {
  asm volatile("s_waitcnt lgkmcnt(0)" ::: "memory");
  __builtin_amdgcn_s_barrier();
  asm volatile("" ::: "memory");
}

// ---------------- weight prep: bf16 convert, Whh split hi/lo, bias merge ----
__global__ void k_prep(const float* __restrict__ Wih, const float* __restrict__ Whh,
                       const float* __restrict__ bih, const float* __restrict__ bhh,
                       u16* __restrict__ wih_b, u16* __restrict__ whh_hi,
                       u16* __restrict__ whh_lo, float* __restrict__ bcat) {
  size_t stride = (size_t)gridDim.x * blockDim.x;
  size_t i0 = (size_t)blockIdx.x * blockDim.x + threadIdx.x;
  const size_t n_ih = (size_t)2 * 2 * G4 * EMBD;  // [l][d][4H][E]
  for (size_t i = i0; i < n_ih; i += stride) wih_b[i] = f2bf(Wih[i]);
  const size_t n_hh = (size_t)2 * 2 * G4 * HID;   // [l][d][4H][H]
  for (size_t i = i0; i < n_hh; i += stride) {
    float w = Whh[i];
    u16 hi = f2bf(w);
    whh_hi[i] = hi;
    whh_lo[i] = f2bf(w - bf2f(hi));
  }
  for (size_t i = i0; i < 2 * 4096; i += stride) {
    size_t l = i >> 12, col = i & 4095;  // col = d*2048+g*512+u
    bcat[i] = bih[l * 4096 + col] + bhh[l * 4096 + col];
  }
}

// ---------------- embedding gather -> bf16 X [T*B, 1024] --------------------
__global__ void k_gather(const int* __restrict__ inp, const float* __restrict__ emb,
                         u16* __restrict__ X) {
  int row = blockIdx.x;  // t*32 + b
  int t = row >> 5, b = row & 31;
  int tok = inp[b * T_SEQ + t];
  const float* src = emb + (size_t)tok * EMBD + threadIdx.x * 4;
  float4 v = *reinterpret_cast<const float4*>(src);
  ushort4 o;
  o.x = f2bf(v.x); o.y = f2bf(v.y); o.z = f2bf(v.z); o.w = f2bf(v.w);
  *reinterpret_cast<ushort4*>(X + (size_t)row * EMBD + threadIdx.x * 4) = o;
}

// ---------------- xp GEMM: C[M,4096] = A[M,1024] @ B[4096,1024]^T + bias ----
#define GBM 128
#define GBN 128
#define GBK 64
__global__ __launch_bounds__(256) void k_gemm(const u16* __restrict__ A,
                                              const u16* __restrict__ B,
                                              const float* __restrict__ bias,
                                              u16* __restrict__ C) {
  __shared__ u16 As[GBM][GBK];
  __shared__ u16 Bs[GBN][GBK];
  const int Kdim = 1024, Ndim = 4096;
  int bm = blockIdx.x, bn = blockIdx.y;
  int tid = threadIdx.x;
  int lane = tid & 63, wave = tid >> 6;
  int wm = wave >> 1, wn = wave & 1;
  int l15 = lane & 15, klo = (lane >> 4) * 8;
  f32x4 acc[4][4] = {};
  for (int k0 = 0; k0 < Kdim; k0 += GBK) {
#pragma unroll
    for (int s = 0; s < 4; s++) {
      int seg = tid + s * 256;
      int r = seg >> 3, cs = (seg & 7) * 8;
      *reinterpret_cast<short8*>(&As[r][cs]) =
          *reinterpret_cast<const short8*>(A + (size_t)(bm * GBM + r) * Kdim + k0 + cs);
      *reinterpret_cast<short8*>(&Bs[r][cs]) =
          *reinterpret_cast<const short8*>(B + (size_t)(bn * GBN + r) * Kdim + k0 + cs);
    }
    __syncthreads();
#pragma unroll
    for (int kk = 0; kk < GBK; kk += 32) {
      short8 af[4], bfb[4];
#pragma unroll
      for (int i = 0; i < 4; i++)
        af[i] = *reinterpret_cast<const short8*>(&As[wm * 64 + i * 16 + l15][kk + klo]);
#pragma unroll
      for (int j = 0; j < 4; j++)
        bfb[j] = *reinterpret_cast<const short8*>(&Bs[wn * 64 + j * 16 + l15][kk + klo]);
#pragma unroll
      for (int i = 0; i < 4; i++)
#pragma unroll
        for (int j = 0; j < 4; j++)
          acc[i][j] = mfma16(af[i], bfb[j], acc[i][j]);
    }
    __syncthreads();
  }
  int lg4 = (lane >> 4) * 4;
#pragma unroll
  for (int i = 0; i < 4; i++) {
#pragma unroll
    for (int j = 0; j < 4; j++) {
      int n = bn * GBN + wn * 64 + j * 16 + l15;
      float bv = bias[n];
#pragma unroll
      for (int r = 0; r < 4; r++) {
        int m = bm * GBM + wm * 64 + i * 16 + lg4 + r;
        C[(size_t)m * Ndim + n] = f2bf(acc[i][j][r] + bv);
      }
    }
  }
}

// ---------------- recurrent layer: 64 WGs (32/dir), K-split waves -----------
// v5 "data-is-the-flag": ypk pre-sentineled 0xFFFFFFFF (impossible packed h).
// Consumers poll h DIRECTLY with LLC-bypass loads (sc0 sc1); no flags, no
// store-drain, no acquire inv. Raw LDS-only barriers. xq issued via raw asm
// right after poll (hides under MFMA), consumed late in reduce.
__global__ __launch_bounds__(256, 1) void k_lstm8(const u16* __restrict__ xp,
                                                  const u16* __restrict__ whh_hi,
                                                  const u16* __restrict__ whh_lo,
                                                  u32* __restrict__ ypk,
                                                  u16* __restrict__ yh,
                                                  int write_yh) {
  int blk = blockIdx.x;
  int dir = blk >> 5, slice = blk & 31;
  int tid = threadIdx.x, wave = tid >> 6, lane = tid & 63;
  int u0 = slice * 16;
  int l15 = lane & 15, lg = lane >> 4;
  int klo = lg * 8;

  // Weight fragments: [gate ct][kt], K-cols wave*128 + kt*32 + klo .. +7
  f32x4 whf[4][4], wlf[4][4];
#pragma unroll
  for (int ct = 0; ct < 4; ct++) {
    size_t wr = ((size_t)dir * G4 + ct * HID + u0 + l15) * HID + wave * 128 + klo;
#pragma unroll
    for (int kt = 0; kt < 4; kt++) {
      whf[ct][kt] = *reinterpret_cast<const f32x4*>(whh_hi + wr + kt * 32);
      wlf[ct][kt] = *reinterpret_cast<const f32x4*>(whh_lo + wr + kt * 32);
    }
  }
#pragma unroll
  for (int ct = 0; ct < 4; ct++)
#pragma unroll
    for (int kt = 0; kt < 4; kt++) {
      asm volatile("" : "+v"(whf[ct][kt]));
      asm volatile("" : "+v"(wlf[ct][kt]));
    }

  __shared__ float pgx[4][NB][16][5];  // [gate][b][uu][wave+pad]
  float cst[2] = {0.f, 0.f};
  int bj[2], uj[2];
#pragma unroll
  for (int j = 0; j < 2; j++) {
    int p = tid + 256 * j;
    uj[j] = p & 15;
    bj[j] = p >> 4;
  }

  for (int s = 0; s < T_SEQ; s++) {
    int trow = dir ? (T_SEQ - 1 - s) : s;
    short8 ah[2][4], al[2][4];
    if (s > 0) {
      int prow = dir ? (T_SEQ - s) : (s - 1);
      const u32* yb = ypk + ((size_t)prow * NB + l15) * 1024 + dir * HID + wave * 128 + klo;
      uint4 hb[2][4][2];
      // ---- data-poll: retry until no lane sees the sentinel ----
      while (true) {
#pragma unroll
        for (int mt = 0; mt < 2; mt++) {
          const u32* pb = yb + (size_t)mt * 16 * 1024;
#pragma unroll
          for (int kt = 0; kt < 4; kt++) {
            asm volatile("global_load_dwordx4 %0, %1, off offset:%2 sc0 sc1"
                         : "=&v"(hb[mt][kt][0]) : "v"(pb), "i"(kt * 128));
            asm volatile("global_load_dwordx4 %0, %1, off offset:%2 sc0 sc1"
                         : "=&v"(hb[mt][kt][1]) : "v"(pb), "i"(kt * 128 + 16));
          }
        }
        asm volatile("s_waitcnt vmcnt(0)" ::: "memory");
        __builtin_amdgcn_sched_barrier(0);
        u32 mx = 0;  // SENTW == u32 max: any sentinel word makes mx == SENTW
#pragma unroll
        for (int mt = 0; mt < 2; mt++)
#pragma unroll
          for (int kt = 0; kt < 4; kt++)
#pragma unroll
            for (int h2 = 0; h2 < 2; h2++) {
              uint4 v = hb[mt][kt][h2];
              mx = max(mx, max(max(v.x, v.y), max(v.z, v.w)));
            }
        if (__all(mx != SENTW)) break;
      }
      // unpack hi|lo via byte-perms
#pragma unroll
      for (int mt = 0; mt < 2; mt++)
#pragma unroll
        for (int kt = 0; kt < 4; kt++) {
          uint4 a = hb[mt][kt][0], b = hb[mt][kt][1];
          u32 v8[8] = {a.x, a.y, a.z, a.w, b.x, b.y, b.z, b.w};
          union { short8 s8; u32 u[4]; } uh, ul;
#pragma unroll
          for (int i = 0; i < 4; i++) {
            uh.u[i] = __builtin_amdgcn_perm(v8[2 * i + 1], v8[2 * i], 0x07060302u);
            ul.u[i] = __builtin_amdgcn_perm(v8[2 * i + 1], v8[2 * i], 0x05040100u);
          }
          ah[mt][kt] = uh.s8;
          al[mt][kt] = ul.s8;
        }
    }
    // ---- issue xq loads now (no wait): latency hides under MFMA phase ----
    u32 xqr[2][4];
#pragma unroll
    for (int j = 0; j < 2; j++) {
      const u16* xb = xp + (size_t)(trow * NB + bj[j]) * XPW + dir * 2048 + u0 + uj[j];
#pragma unroll
      for (int g = 0; g < 4; g++)
        asm volatile("global_load_ushort %0, %1, off offset:%2"
                     : "=&v"(xqr[j][g]) : "v"(xb), "i"(g * HID * 2));
    }
    if (s > 0) {
      f32x4 accM[2][4], accC[2][4];
#pragma unroll
      for (int mt = 0; mt < 2; mt++)
#pragma unroll
        for (int ct = 0; ct < 4; ct++) {
          accM[mt][ct] = (f32x4){0.f, 0.f, 0.f, 0.f};
          accC[mt][ct] = (f32x4){0.f, 0.f, 0.f, 0.f};
        }
#pragma unroll
      for (int kt = 0; kt < 4; kt++)
#pragma unroll
        for (int mt = 0; mt < 2; mt++)
#pragma unroll
          for (int ct = 0; ct < 4; ct++) {
            short8 wh = __builtin_bit_cast(short8, whf[ct][kt]);
            short8 wl = __builtin_bit_cast(short8, wlf[ct][kt]);
            accM[mt][ct] = mfma16(ah[mt][kt], wh, accM[mt][ct]);
            accC[mt][ct] = mfma16(al[mt][kt], wh, accC[mt][ct]);
            accC[mt][ct] = mfma16(ah[mt][kt], wl, accC[mt][ct]);
          }
#pragma unroll
      for (int mt = 0; mt < 2; mt++)
#pragma unroll
        for (int ct = 0; ct < 4; ct++) {
          f32x4 v4 = accM[mt][ct] + accC[mt][ct];
#pragma unroll
          for (int r = 0; r < 4; r++)
            pgx[ct][mt * 16 + lg * 4 + r][l15][wave] = v4[r];
        }
    }
    barrier_lds();  // pgx writes visible; NO vmcnt drain (stores ride out)
    // consume xq now (issued ~1 MFMA-phase ago)
    asm volatile("s_waitcnt vmcnt(0)" ::: "memory");
    __builtin_amdgcn_sched_barrier(0);
#pragma unroll
    for (int j = 0; j < 2; j++) {
      int b = bj[j], uu = uj[j];
      float gs[4];
#pragma unroll
      for (int g = 0; g < 4; g++) {
        float v = bf2f((u16)xqr[j][g]);
        if (s > 0)
          v += (pgx[g][b][uu][0] + pgx[g][b][uu][1]) +
               (pgx[g][b][uu][2] + pgx[g][b][uu][3]);
        gs[g] = v;
      }
      float iv = sigm(gs[0]);
      float fv = sigm(gs[1]);
      float gv = fast_tanh(gs[2]);
      float ov = sigm(gs[3]);
      float c = fv * cst[j] + iv * gv;
      cst[j] = c;
      float h = ov * fast_tanh(c);
      u16 hh = f2bf(h);
      u16 hl = f2bf(h - bf2f(hh));
      size_t yo = ((size_t)trow * NB + b) * 1024 + dir * HID + u0 + uu;
      __hip_atomic_store(ypk + yo, ((u32)hh << 16) | hl, __ATOMIC_RELAXED,
                         __HIP_MEMORY_SCOPE_AGENT);
      if (write_yh) yh[yo] = hh;  // cross-kernel only (end-of-dispatch flush)
    }
    barrier_lds();  // protect pgx reads before next step's writes
  }
}

// ---------------- final pooled dot ------------------------------------------
__global__ void k_out(const u32* __restrict__ ypk, const float* __restrict__ wout,
                      const float* __restrict__ bout, float* __restrict__ out) {
  int b = blockIdx.x;
  __shared__ float red[256];
  float s = 0.f;
  for (int c = threadIdx.x; c < 1024; c += 256) {
    size_t row = (c < 512) ? ((size_t)(T_SEQ - 1) * NB + b) : (size_t)b;
    u32 pk = ypk[row * 1024 + c];
    float h = bf2f((u16)(pk >> 16)) + bf2f((u16)(pk & 0xFFFFu));
    s += h * wout[c];
  }
  red[threadIdx.x] = s;
  __syncthreads();
  for (int st = 128; st > 0; st >>= 1) {
    if (threadIdx.x < st) red[threadIdx.x] += red[threadIdx.x + st];
    __syncthreads();
  }
  if (threadIdx.x == 0) out[b] = red[0] + bout[0];
}

extern "C" void kernel_launch(void* const* d_in, const int* in_sizes, int n_in,
                              void* d_out, int out_size, void* d_ws, size_t ws_size,
                              hipStream_t stream) {
  const int*   inp  = (const int*)d_in[0];
  const float* emb  = (const float*)d_in[1];
  const float* Wih  = (const float*)d_in[2];
  const float* Whh  = (const float*)d_in[3];
  const float* bih  = (const float*)d_in[4];
  const float* bhh  = (const float*)d_in[5];
  const float* Wout = (const float*)d_in[6];
  const float* bout = (const float*)d_in[7];
  float* out = (float*)d_out;
  char* ws = (char*)d_ws;

  const size_t SZ_XP  = (size_t)NROWS * XPW * 2;       // 134 MB
  const size_t SZ_YPK = (size_t)NROWS * 1024 * 4;      // 67 MB
  const size_t SZ_YH  = (size_t)NROWS * 1024 * 2;      // 33.5 MB
  const size_t SZ_WIH = (size_t)2 * 4096 * 1024 * 2;
  const size_t SZ_WHH = (size_t)2 * 2 * G4 * HID * 2;
  size_t off = 0;
  auto alloc = [&](size_t n) { size_t o = off; off += (n + 255) & ~(size_t)255; return o; };
  size_t o_xp   = alloc(SZ_XP);
  size_t o_ypkA = alloc(SZ_YPK);
  size_t o_y1h  = alloc(SZ_YH);   // \ contiguous pair: reused as ypkB (67MB)
  size_t o_x1   = alloc(SZ_YH);   // /  after GEMM-2 consumes y1h
  size_t o_wih  = alloc(SZ_WIH);
  size_t o_whhh = alloc(SZ_WHH);
  size_t o_whhl = alloc(SZ_WHH);
  size_t o_bc   = alloc(2 * 4096 * sizeof(float));
  if (ws_size < off) return;

  u16* xp   = (u16*)(ws + o_xp);
  u32* ypkA = (u32*)(ws + o_ypkA);
  u16* y1h  = (u16*)(ws + o_y1h);
  u16* x1   = (u16*)(ws + o_x1);
  u32* ypkB = (u32*)(ws + o_y1h);  // alias over dead y1h+x1
  u16* wihb = (u16*)(ws + o_wih);
  u16* whhh = (u16*)(ws + o_whhh);
  u16* whhl = (u16*)(ws + o_whhl);
  float* bc = (float*)(ws + o_bc);

  hipMemsetAsync(ypkA, 0xFF, SZ_YPK, stream);  // sentinel layer-1 h buffer
  k_prep<<<4096, 256, 0, stream>>>(Wih, Whh, bih, bhh, wihb, whhh, whhl, bc);
  k_gather<<<NROWS, 256, 0, stream>>>(inp, emb, x1);
  k_gemm<<<dim3(NROWS / GBM, XPW / GBN), 256, 0, stream>>>(x1, wihb, bc, xp);
  k_lstm8<<<2 * WPD, 256, 0, stream>>>(xp, whhh, whhl, ypkA, y1h, 1);
  k_gemm<<<dim3(NROWS / GBM, XPW / GBN), 256, 0, stream>>>(
      y1h, wihb + (size_t)4096 * 1024, bc + 4096, xp);
  hipMemsetAsync(ypkB, 0xFF, SZ_YPK, stream);  // sentinel layer-2 h buffer
  k_lstm8<<<2 * WPD, 256, 0, stream>>>(xp, whhh + (size_t)2 * G4 * HID,
                                       whhl + (size_t)2 * G4 * HID, ypkB, y1h, 0);
  k_out<<<NB, 256, 0, stream>>>(ypkB, Wout, bout, out);
}